// Round 2
// baseline (17882.430 us; speedup 1.0000x reference)
//
#include <hip/hip_runtime.h>
#include <math.h>

#define BB     2
#define SS     2048
#define HH     768
#define NHEAD  12
#define DHEAD  64
#define FFD    3072
#define NLAYER 2
#define MTOK   (BB*SS)   // 4096 rows

// ---------------------------------------------------------------------------
// C[M,N] = act(A[M,K] @ W[K,N] + bias[N]); act = exact GELU if gelu!=0
// 64x64 tile / block of 256 threads, BK=16, 4x4 micro-tile, fp32 accumulate.
// ---------------------------------------------------------------------------
__global__ __launch_bounds__(256)
void gemm_bias(const float* __restrict__ A, const float* __restrict__ W,
               const float* __restrict__ bias, float* __restrict__ C,
               int M, int N, int K, int gelu)
{
    __shared__ float sA[16][65];   // [k][m], +1 pad
    __shared__ float sW[16][65];   // [k][n], +1 pad
    const int tid = threadIdx.x;
    const int m0 = blockIdx.y * 64;
    const int n0 = blockIdx.x * 64;
    const int tx = tid & 15, ty = tid >> 4;

    const int ar = tid >> 4;   // 0..15 (A tile row group)
    const int ac = tid & 15;   // 0..15 (A tile k col)
    const int wr = tid >> 6;   // 0..3  (W tile k row group)
    const int wc = tid & 63;   // 0..63 (W tile n col)

    float acc[4][4];
#pragma unroll
    for (int i = 0; i < 4; i++)
#pragma unroll
        for (int j = 0; j < 4; j++) acc[i][j] = 0.f;

    for (int k0 = 0; k0 < K; k0 += 16) {
#pragma unroll
        for (int i = 0; i < 4; i++)
            sA[ac][ar + i*16] = A[(size_t)(m0 + ar + i*16)*K + k0 + ac];
#pragma unroll
        for (int j = 0; j < 4; j++)
            sW[wr + j*4][wc] = W[(size_t)(k0 + wr + j*4)*N + n0 + wc];
        __syncthreads();
#pragma unroll
        for (int kk = 0; kk < 16; kk++) {
            float a0 = sA[kk][ty*4+0], a1 = sA[kk][ty*4+1];
            float a2 = sA[kk][ty*4+2], a3 = sA[kk][ty*4+3];
            float w0 = sW[kk][tx*4+0], w1 = sW[kk][tx*4+1];
            float w2 = sW[kk][tx*4+2], w3 = sW[kk][tx*4+3];
            acc[0][0] += a0*w0; acc[0][1] += a0*w1; acc[0][2] += a0*w2; acc[0][3] += a0*w3;
            acc[1][0] += a1*w0; acc[1][1] += a1*w1; acc[1][2] += a1*w2; acc[1][3] += a1*w3;
            acc[2][0] += a2*w0; acc[2][1] += a2*w1; acc[2][2] += a2*w2; acc[2][3] += a2*w3;
            acc[3][0] += a3*w0; acc[3][1] += a3*w1; acc[3][2] += a3*w2; acc[3][3] += a3*w3;
        }
        __syncthreads();
    }

#pragma unroll
    for (int i = 0; i < 4; i++) {
        const int row = m0 + ty*4 + i;
#pragma unroll
        for (int j = 0; j < 4; j++) {
            const int col = n0 + tx*4 + j;
            float v = acc[i][j] + bias[col];
            if (gelu) v = 0.5f * v * (1.f + erff(v * 0.70710678118f));
            C[(size_t)row * N + col] = v;
        }
    }
}

// ---------------------------------------------------------------------------
// One block per (b, h, q): scores row (S) in LDS, softmax, probs @ V.
// Q/K/V layout: [B*S, H] with head h at columns h*DHEAD .. h*DHEAD+63.
// ---------------------------------------------------------------------------
__global__ __launch_bounds__(256)
void attn_row(const float* __restrict__ Q, const float* __restrict__ Km,
              const float* __restrict__ Vm, const float* __restrict__ mask,
              const float* __restrict__ biasM, const float* __restrict__ coefp,
              float* __restrict__ CTX)
{
    const int q = blockIdx.x, h = blockIdx.y, b = blockIdx.z;
    const int tid = threadIdx.x;
    __shared__ float sc[SS];       // 8 KB scores row
    __shared__ float qv[DHEAD];
    __shared__ float rbuf[256];

    const float coef = coefp[0];
    if (tid < DHEAD)
        qv[tid] = Q[((size_t)(b*SS + q))*HH + h*DHEAD + tid];
    __syncthreads();

    const float* Kbase = Km + (size_t)(b*SS)*HH + h*DHEAD;
    float mx = -1e30f;
    for (int k = tid; k < SS; k += 256) {
        const float* kr = Kbase + (size_t)k*HH;
        float dot = 0.f;
#pragma unroll
        for (int d = 0; d < DHEAD; d++) dot += qv[d] * kr[d];
        float sval = dot * 0.125f
                   + biasM[(size_t)q*SS + k] * coef
                   + (1.f - mask[b*SS + k]) * (-10000.0f);
        sc[k] = sval;
        mx = fmaxf(mx, sval);
    }
    rbuf[tid] = mx; __syncthreads();
    for (int off = 128; off > 0; off >>= 1) {
        if (tid < off) rbuf[tid] = fmaxf(rbuf[tid], rbuf[tid + off]);
        __syncthreads();
    }
    mx = rbuf[0]; __syncthreads();

    float sum = 0.f;
    for (int k = tid; k < SS; k += 256) {
        float e = __expf(sc[k] - mx);
        sc[k] = e;
        sum += e;
    }
    rbuf[tid] = sum; __syncthreads();
    for (int off = 128; off > 0; off >>= 1) {
        if (tid < off) rbuf[tid] += rbuf[tid + off];
        __syncthreads();
    }
    const float inv = 1.f / rbuf[0]; __syncthreads();

    // ctx: tid -> (d = tid&63, k-chunk = tid>>6 of 512)
    const int d = tid & 63, ch = tid >> 6;
    const float* Vbase = Vm + (size_t)(b*SS)*HH + h*DHEAD;
    float acc = 0.f;
    for (int k = ch*512; k < (ch+1)*512; k++)
        acc += sc[k] * Vbase[(size_t)k*HH + d];
    rbuf[tid] = acc; __syncthreads();
    if (tid < 64) {
        float o = (rbuf[tid] + rbuf[tid+64] + rbuf[tid+128] + rbuf[tid+192]) * inv;
        CTX[((size_t)(b*SS + q))*HH + h*DHEAD + tid] = o;
    }
}

// ---------------------------------------------------------------------------
// Out[row] = LayerNorm(A[row] + R[row]) * g + beta    (one block per row)
// Safe for Out == A (row fully staged into LDS before any write).
// ---------------------------------------------------------------------------
__global__ __launch_bounds__(256)
void add_ln(const float* __restrict__ A, const float* __restrict__ R,
            const float* __restrict__ g, const float* __restrict__ beta,
            float* __restrict__ Out)
{
    const int row = blockIdx.x;
    const int tid = threadIdx.x;
    __shared__ float vals[HH];
    __shared__ float rbuf[256];

    float s = 0.f;
    for (int c = tid; c < HH; c += 256) {
        float v = A[(size_t)row*HH + c] + R[(size_t)row*HH + c];
        vals[c] = v;
        s += v;
    }
    rbuf[tid] = s; __syncthreads();
    for (int off = 128; off > 0; off >>= 1) {
        if (tid < off) rbuf[tid] += rbuf[tid + off];
        __syncthreads();
    }
    const float mu = rbuf[0] * (1.f / HH); __syncthreads();

    float s2 = 0.f;
    for (int c = tid; c < HH; c += 256) {
        float dlt = vals[c] - mu;
        s2 += dlt * dlt;
    }
    rbuf[tid] = s2; __syncthreads();
    for (int off = 128; off > 0; off >>= 1) {
        if (tid < off) rbuf[tid] += rbuf[tid + off];
        __syncthreads();
    }
    const float rstd = rsqrtf(rbuf[0] * (1.f / HH) + 1e-12f); __syncthreads();

    for (int c = tid; c < HH; c += 256) {
        float v = (vals[c] - mu) * rstd * g[c] + beta[c];
        Out[(size_t)row*HH + c] = v;
    }
}

// ---------------------------------------------------------------------------
extern "C" void kernel_launch(void* const* d_in, const int* in_sizes, int n_in,
                              void* d_out, int out_size, void* d_ws, size_t ws_size,
                              hipStream_t stream)
{
    const float* hs    = (const float*)d_in[0];
    const float* mask  = (const float*)d_in[1];
    const float* biasM = (const float*)d_in[2];
    const float* coef  = (const float*)d_in[3];
    const float* Wq    = (const float*)d_in[4];
    const float* bq    = (const float*)d_in[5];
    const float* Wk    = (const float*)d_in[6];
    const float* bk    = (const float*)d_in[7];
    const float* Wv    = (const float*)d_in[8];
    const float* bv    = (const float*)d_in[9];
    const float* Wo    = (const float*)d_in[10];
    const float* bo    = (const float*)d_in[11];
    const float* ln1g  = (const float*)d_in[12];
    const float* ln1b  = (const float*)d_in[13];
    const float* Wi    = (const float*)d_in[14];
    const float* bi    = (const float*)d_in[15];
    const float* Wo2   = (const float*)d_in[16];
    const float* bo2   = (const float*)d_in[17];
    const float* ln2g  = (const float*)d_in[18];
    const float* ln2b  = (const float*)d_in[19];

    const size_t sH = (size_t)MTOK * HH;   // 3,145,728 elems
    float* ws = (float*)d_ws;
    float* X    = ws;            // 0 .. sH
    float* X2   = X  + sH;       // residual after ln1
    float* Qb   = X2 + sH;
    float* Kb   = Qb + sH;
    float* Vb   = Kb + sH;
    float* CTXb = Vb + sH;       // total 6*sH = 72 MB
    float* TMP  = Qb;            // alias: Q dead when attn-out proj runs
    float* INTER= Qb;            // alias: 4*sH spanning Qb..CTXb (all dead)
    float* TMP2 = X;             // alias: X dead after ln1 residual consumed

    hipMemcpyAsync(X, hs, sH * sizeof(float), hipMemcpyDeviceToDevice, stream);

    const dim3 blk(256);
    const dim3 gP(HH/64,  MTOK/64);   // projections  [12, 64]
    const dim3 gI(FFD/64, MTOK/64);   // FFN up       [48, 64]
    const dim3 gAttn(SS, NHEAD, BB);

    for (int i = 0; i < NLAYER; i++) {
        const size_t wOff = (size_t)i*HH*HH, bOff = (size_t)i*HH;
        gemm_bias<<<gP, blk, 0, stream>>>(X, Wq + wOff, bq + bOff, Qb, MTOK, HH, HH, 0);
        gemm_bias<<<gP, blk, 0, stream>>>(X, Wk + wOff, bk + bOff, Kb, MTOK, HH, HH, 0);
        gemm_bias<<<gP, blk, 0, stream>>>(X, Wv + wOff, bv + bOff, Vb, MTOK, HH, HH, 0);
        attn_row<<<gAttn, blk, 0, stream>>>(Qb, Kb, Vb, mask, biasM, coef, CTXb);
        gemm_bias<<<gP, blk, 0, stream>>>(CTXb, Wo + wOff, bo + bOff, TMP, MTOK, HH, HH, 0);
        add_ln<<<MTOK, blk, 0, stream>>>(TMP, X, ln1g + bOff, ln1b + bOff, X2);
        gemm_bias<<<gI, blk, 0, stream>>>(X2, Wi + (size_t)i*HH*FFD, bi + (size_t)i*FFD,
                                          INTER, MTOK, FFD, HH, 1);
        gemm_bias<<<gP, blk, 0, stream>>>(INTER, Wo2 + (size_t)i*FFD*HH, bo2 + bOff,
                                          TMP2, MTOK, HH, FFD, 0);
        add_ln<<<MTOK, blk, 0, stream>>>(TMP2, X2, ln2g + bOff, ln2b + bOff, X);
    }

    hipMemcpyAsync(d_out, X, sH * sizeof(float), hipMemcpyDeviceToDevice, stream);
}

// Round 3
// 2866.955 us; speedup vs baseline: 6.2374x; 6.2374x over previous
//
#include <hip/hip_runtime.h>
#include <hip/hip_bf16.h>
#include <math.h>

#define BB     2
#define SS     2048
#define HH     768
#define NHEAD  12
#define DHEAD  64
#define FFD    3072
#define NLAYER 2
#define MTOK   (BB*SS)   // 4096 rows

typedef __attribute__((ext_vector_type(8))) short bf16x8;
typedef __attribute__((ext_vector_type(4))) float f32x4;

__device__ __forceinline__ short f2bs(float f) {
    union { float f; unsigned u; } v; v.f = f;
    unsigned r = v.u + 0x7FFF + ((v.u >> 16) & 1);   // RNE to bf16
    return (short)(r >> 16);
}

// ---------------------------------------------------------------------------
// C[M,N] = act(A[M,K] @ W[K,N] + bias[N]); act = exact GELU if gelu!=0
// 64x64 tile / block of 256 threads, BK=16, 4x4 micro-tile, fp32 accumulate.
// ---------------------------------------------------------------------------
__global__ __launch_bounds__(256)
void gemm_bias(const float* __restrict__ A, const float* __restrict__ W,
               const float* __restrict__ bias, float* __restrict__ C,
               int M, int N, int K, int gelu)
{
    __shared__ float sA[16][65];
    __shared__ float sW[16][65];
    const int tid = threadIdx.x;
    const int m0 = blockIdx.y * 64;
    const int n0 = blockIdx.x * 64;
    const int tx = tid & 15, ty = tid >> 4;

    const int ar = tid >> 4;
    const int ac = tid & 15;
    const int wr = tid >> 6;
    const int wc = tid & 63;

    float acc[4][4];
#pragma unroll
    for (int i = 0; i < 4; i++)
#pragma unroll
        for (int j = 0; j < 4; j++) acc[i][j] = 0.f;

    for (int k0 = 0; k0 < K; k0 += 16) {
#pragma unroll
        for (int i = 0; i < 4; i++)
            sA[ac][ar + i*16] = A[(size_t)(m0 + ar + i*16)*K + k0 + ac];
#pragma unroll
        for (int j = 0; j < 4; j++)
            sW[wr + j*4][wc] = W[(size_t)(k0 + wr + j*4)*N + n0 + wc];
        __syncthreads();
#pragma unroll
        for (int kk = 0; kk < 16; kk++) {
            float a0 = sA[kk][ty*4+0], a1 = sA[kk][ty*4+1];
            float a2 = sA[kk][ty*4+2], a3 = sA[kk][ty*4+3];
            float w0 = sW[kk][tx*4+0], w1 = sW[kk][tx*4+1];
            float w2 = sW[kk][tx*4+2], w3 = sW[kk][tx*4+3];
            acc[0][0] += a0*w0; acc[0][1] += a0*w1; acc[0][2] += a0*w2; acc[0][3] += a0*w3;
            acc[1][0] += a1*w0; acc[1][1] += a1*w1; acc[1][2] += a1*w2; acc[1][3] += a1*w3;
            acc[2][0] += a2*w0; acc[2][1] += a2*w1; acc[2][2] += a2*w2; acc[2][3] += a2*w3;
            acc[3][0] += a3*w0; acc[3][1] += a3*w1; acc[3][2] += a3*w2; acc[3][3] += a3*w3;
        }
        __syncthreads();
    }

#pragma unroll
    for (int i = 0; i < 4; i++) {
        const int row = m0 + ty*4 + i;
#pragma unroll
        for (int j = 0; j < 4; j++) {
            const int col = n0 + tx*4 + j;
            float v = acc[i][j] + bias[col];
            if (gelu) v = 0.5f * v * (1.f + erff(v * 0.70710678118f));
            C[(size_t)row * N + col] = v;
        }
    }
}

// ---------------------------------------------------------------------------
// Flash attention, bf16 MFMA. Block = (q-tile of 64, head, batch), 4 waves.
// Wave w owns queries [w*16, w*16+16). Loop over 32 K-tiles of 64 keys:
//   stage K[key][dim], Vt[dim][key] bf16 in LDS (stride 72 to spread banks),
//   S = QK^T (mfma 16x16x32), bias/mask/scale in C-layout regs,
//   online softmax fully in regs (C row = (lane>>4)*4+reg for BOTH the score
//   frags and the O frags, so m/l/alpha stay per-lane), P -> LDS (C-layout
//   write, A-layout b128 read), O += P@V.
// ---------------------------------------------------------------------------
__global__ __launch_bounds__(256)
void attn_fused(const float* __restrict__ Q, const float* __restrict__ K,
                const float* __restrict__ V, const float* __restrict__ mask,
                const float* __restrict__ biasM, const float* __restrict__ coefp,
                float* __restrict__ CTX)
{
    __shared__ short sK [64*72];
    __shared__ short sVt[64*72];
    __shared__ short sP [64*72];
    __shared__ float sMask[64];

    const int q0  = blockIdx.x * 64;
    const int h   = blockIdx.y;
    const int b   = blockIdx.z;
    const int tid = threadIdx.x;
    const int w   = tid >> 6;       // wave 0..3
    const int lane = tid & 63;
    const int l16 = lane & 15;      // MFMA m/n index
    const int g   = lane >> 4;      // quad 0..3

    const float coef  = coefp[0];
    const float scale = 0.125f;     // 1/sqrt(64)

    // Q A-fragments, held in registers the whole kernel
    bf16x8 aQ0, aQ1;
    {
        const float* qrow = Q + ((size_t)(b*SS) + q0 + w*16 + l16) * HH + h*DHEAD;
#pragma unroll
        for (int j = 0; j < 8; j++) aQ0[j] = f2bs(qrow[g*8 + j]);
#pragma unroll
        for (int j = 0; j < 8; j++) aQ1[j] = f2bs(qrow[32 + g*8 + j]);
    }

    f32x4 O[4];                     // O[dblk]: rows g*4+r, cols dblk*16+l16
#pragma unroll
    for (int d = 0; d < 4; d++) O[d] = (f32x4){0.f,0.f,0.f,0.f};
    float m_i[4], l_i[4];
#pragma unroll
    for (int r = 0; r < 4; r++) { m_i[r] = -1e30f; l_i[r] = 0.f; }

    const int srow = tid >> 2;      // staging: key row 0..63
    const int scg  = tid & 3;       // staging: col group (16 dims)

    for (int k0 = 0; k0 < SS; k0 += 64) {
        // ---- stage K tile as [key][dim] bf16 (vector write) ----
        {
            const float* krow = K + ((size_t)(b*SS) + k0 + srow) * HH + h*DHEAD + scg*16;
            short tmp[16];
#pragma unroll
            for (int i = 0; i < 16; i++) tmp[i] = f2bs(krow[i]);
            short* dst = &sK[srow*72 + scg*16];
#pragma unroll
            for (int i = 0; i < 16; i++) dst[i] = tmp[i];
        }
        // ---- stage V transposed as [dim][key] bf16 (scalar scatter) ----
        {
            const float* vrow = V + ((size_t)(b*SS) + k0 + srow) * HH + h*DHEAD + scg*16;
#pragma unroll
            for (int i = 0; i < 16; i++)
                sVt[(scg*16 + i)*72 + srow] = f2bs(vrow[i]);
        }
        if (tid < 64) sMask[tid] = (1.f - mask[b*SS + k0 + tid]) * (-10000.0f);
        __syncthreads();

        // ---- S = QK^T * scale + bias*coef + maskadd (scores in regs) ----
        float S[4][4];              // [t16][reg]
#pragma unroll
        for (int t16 = 0; t16 < 4; t16++) {
            bf16x8 b0 = *(const bf16x8*)&sK[(t16*16 + l16)*72 + g*8];
            bf16x8 b1 = *(const bf16x8*)&sK[(t16*16 + l16)*72 + 32 + g*8];
            f32x4 c = (f32x4){0.f,0.f,0.f,0.f};
            c = __builtin_amdgcn_mfma_f32_16x16x32_bf16(aQ0, b0, c, 0, 0, 0);
            c = __builtin_amdgcn_mfma_f32_16x16x32_bf16(aQ1, b1, c, 0, 0, 0);
            const float madd = sMask[t16*16 + l16];
            const int   kcol = k0 + t16*16 + l16;
#pragma unroll
            for (int r = 0; r < 4; r++) {
                const int qg = q0 + w*16 + g*4 + r;
                S[t16][r] = c[r]*scale + biasM[(size_t)qg*SS + kcol]*coef + madd;
            }
        }

        // ---- online softmax (per reg = per query row), all in regs ----
#pragma unroll
        for (int r = 0; r < 4; r++) {
            float mx = fmaxf(fmaxf(S[0][r], S[1][r]), fmaxf(S[2][r], S[3][r]));
            mx = fmaxf(mx, __shfl_xor(mx, 1));
            mx = fmaxf(mx, __shfl_xor(mx, 2));
            mx = fmaxf(mx, __shfl_xor(mx, 4));
            mx = fmaxf(mx, __shfl_xor(mx, 8));
            const float mnew  = fmaxf(m_i[r], mx);
            const float alpha = __expf(m_i[r] - mnew);
            float rs = 0.f;
#pragma unroll
            for (int t16 = 0; t16 < 4; t16++) {
                float p = __expf(S[t16][r] - mnew);
                S[t16][r] = p;
                rs += p;
            }
            rs += __shfl_xor(rs, 1);
            rs += __shfl_xor(rs, 2);
            rs += __shfl_xor(rs, 4);
            rs += __shfl_xor(rs, 8);
            l_i[r] = l_i[r]*alpha + rs;
            m_i[r] = mnew;
#pragma unroll
            for (int d = 0; d < 4; d++) O[d][r] *= alpha;
        }

        // ---- P: C-layout regs -> LDS (own wave's rows only) ----
#pragma unroll
        for (int t16 = 0; t16 < 4; t16++)
#pragma unroll
            for (int r = 0; r < 4; r++)
                sP[(w*16 + g*4 + r)*72 + t16*16 + l16] = f2bs(S[t16][r]);
        __syncthreads();   // also covers cross-wave nothing; guarantees P visible

        // ---- O += P @ V ----
        bf16x8 aP0 = *(const bf16x8*)&sP[(w*16 + l16)*72 + g*8];
        bf16x8 aP1 = *(const bf16x8*)&sP[(w*16 + l16)*72 + 32 + g*8];
#pragma unroll
        for (int d = 0; d < 4; d++) {
            bf16x8 v0 = *(const bf16x8*)&sVt[(d*16 + l16)*72 + g*8];
            bf16x8 v1 = *(const bf16x8*)&sVt[(d*16 + l16)*72 + 32 + g*8];
            O[d] = __builtin_amdgcn_mfma_f32_16x16x32_bf16(aP0, v0, O[d], 0, 0, 0);
            O[d] = __builtin_amdgcn_mfma_f32_16x16x32_bf16(aP1, v1, O[d], 0, 0, 0);
        }
        __syncthreads();   // before next tile overwrites sK/sVt/sP
    }

    // ---- epilogue: O / l, write fp32 ----
#pragma unroll
    for (int d = 0; d < 4; d++) {
#pragma unroll
        for (int r = 0; r < 4; r++) {
            const float o = O[d][r] / l_i[r];
            CTX[((size_t)(b*SS) + q0 + w*16 + g*4 + r)*HH + h*DHEAD + d*16 + l16] = o;
        }
    }
}

// ---------------------------------------------------------------------------
// Out[row] = LayerNorm(A[row] + R[row]) * g + beta    (one block per row)
// Safe for Out == A (row fully staged into LDS before any write).
// ---------------------------------------------------------------------------
__global__ __launch_bounds__(256)
void add_ln(const float* __restrict__ A, const float* __restrict__ R,
            const float* __restrict__ g, const float* __restrict__ beta,
            float* __restrict__ Out)
{
    const int row = blockIdx.x;
    const int tid = threadIdx.x;
    __shared__ float vals[HH];
    __shared__ float rbuf[256];

    float s = 0.f;
    for (int c = tid; c < HH; c += 256) {
        float v = A[(size_t)row*HH + c] + R[(size_t)row*HH + c];
        vals[c] = v;
        s += v;
    }
    rbuf[tid] = s; __syncthreads();
    for (int off = 128; off > 0; off >>= 1) {
        if (tid < off) rbuf[tid] += rbuf[tid + off];
        __syncthreads();
    }
    const float mu = rbuf[0] * (1.f / HH); __syncthreads();

    float s2 = 0.f;
    for (int c = tid; c < HH; c += 256) {
        float dlt = vals[c] - mu;
        s2 += dlt * dlt;
    }
    rbuf[tid] = s2; __syncthreads();
    for (int off = 128; off > 0; off >>= 1) {
        if (tid < off) rbuf[tid] += rbuf[tid + off];
        __syncthreads();
    }
    const float rstd = rsqrtf(rbuf[0] * (1.f / HH) + 1e-12f); __syncthreads();

    for (int c = tid; c < HH; c += 256) {
        float v = (vals[c] - mu) * rstd * g[c] + beta[c];
        Out[(size_t)row*HH + c] = v;
    }
}

// ---------------------------------------------------------------------------
extern "C" void kernel_launch(void* const* d_in, const int* in_sizes, int n_in,
                              void* d_out, int out_size, void* d_ws, size_t ws_size,
                              hipStream_t stream)
{
    const float* hs    = (const float*)d_in[0];
    const float* mask  = (const float*)d_in[1];
    const float* biasM = (const float*)d_in[2];
    const float* coef  = (const float*)d_in[3];
    const float* Wq    = (const float*)d_in[4];
    const float* bq    = (const float*)d_in[5];
    const float* Wk    = (const float*)d_in[6];
    const float* bk    = (const float*)d_in[7];
    const float* Wv    = (const float*)d_in[8];
    const float* bv    = (const float*)d_in[9];
    const float* Wo    = (const float*)d_in[10];
    const float* bo    = (const float*)d_in[11];
    const float* ln1g  = (const float*)d_in[12];
    const float* ln1b  = (const float*)d_in[13];
    const float* Wi    = (const float*)d_in[14];
    const float* bi    = (const float*)d_in[15];
    const float* Wo2   = (const float*)d_in[16];
    const float* bo2   = (const float*)d_in[17];
    const float* ln2g  = (const float*)d_in[18];
    const float* ln2b  = (const float*)d_in[19];

    const size_t sH = (size_t)MTOK * HH;
    float* ws = (float*)d_ws;
    float* X    = ws;
    float* X2   = X  + sH;
    float* Qb   = X2 + sH;
    float* Kb   = Qb + sH;
    float* Vb   = Kb + sH;
    float* CTXb = Vb + sH;       // 6*sH total = 72 MB
    float* TMP  = Qb;            // alias: Q dead when attn-out proj runs
    float* INTER= Qb;            // alias: 4*sH spanning Qb..CTXb
    float* TMP2 = X;             // alias: X dead after ln1 residual consumed

    hipMemcpyAsync(X, hs, sH * sizeof(float), hipMemcpyDeviceToDevice, stream);

    const dim3 blk(256);
    const dim3 gP(HH/64,  MTOK/64);
    const dim3 gI(FFD/64, MTOK/64);
    const dim3 gA(SS/64, NHEAD, BB);   // [32, 12, 2] = 768 blocks

    for (int i = 0; i < NLAYER; i++) {
        const size_t wOff = (size_t)i*HH*HH, bOff = (size_t)i*HH;
        gemm_bias<<<gP, blk, 0, stream>>>(X, Wq + wOff, bq + bOff, Qb, MTOK, HH, HH, 0);
        gemm_bias<<<gP, blk, 0, stream>>>(X, Wk + wOff, bk + bOff, Kb, MTOK, HH, HH, 0);
        gemm_bias<<<gP, blk, 0, stream>>>(X, Wv + wOff, bv + bOff, Vb, MTOK, HH, HH, 0);
        attn_fused<<<gA, blk, 0, stream>>>(Qb, Kb, Vb, mask, biasM, coef, CTXb);
        gemm_bias<<<gP, blk, 0, stream>>>(CTXb, Wo + wOff, bo + bOff, TMP, MTOK, HH, HH, 0);
        add_ln<<<MTOK, blk, 0, stream>>>(TMP, X, ln1g + bOff, ln1b + bOff, X2);
        gemm_bias<<<gI, blk, 0, stream>>>(X2, Wi + (size_t)i*HH*FFD, bi + (size_t)i*FFD,
                                          INTER, MTOK, FFD, HH, 1);
        gemm_bias<<<gP, blk, 0, stream>>>(INTER, Wo2 + (size_t)i*FFD*HH, bo2 + bOff,
                                          TMP2, MTOK, HH, FFD, 0);
        add_ln<<<MTOK, blk, 0, stream>>>(TMP2, X2, ln2g + bOff, ln2b + bOff, X);
    }

    hipMemcpyAsync(d_out, X, sH * sizeof(float), hipMemcpyDeviceToDevice, stream);
}

// Round 4
// 791.464 us; speedup vs baseline: 22.5941x; 3.6223x over previous
//
#include <hip/hip_runtime.h>
#include <hip/hip_bf16.h>
#include <math.h>

#define BB     2
#define SS     2048
#define HH     768
#define NHEAD  12
#define DHEAD  64
#define FFD    3072
#define NLAYER 2
#define MTOK   (BB*SS)   // 4096 rows

typedef __attribute__((ext_vector_type(8))) short bf16x8;
typedef __attribute__((ext_vector_type(4))) float f32x4;

__device__ __forceinline__ short f2bs(float f) {
    union { float f; unsigned u; } v; v.f = f;
    unsigned r = v.u + 0x7FFF + ((v.u >> 16) & 1);   // RNE to bf16
    return (short)(r >> 16);
}
__device__ __forceinline__ float bs2f(short s) {
    union { unsigned u; float f; } v; v.u = ((unsigned)(unsigned short)s) << 16;
    return v.f;
}
// async 16B/lane global->LDS (lds dst = wave-uniform base + lane*16)
__device__ __forceinline__ void gl2lds16(const short* g, short* l) {
    __builtin_amdgcn_global_load_lds(
        (const __attribute__((address_space(1))) unsigned int*)g,
        (__attribute__((address_space(3))) unsigned int*)l, 16, 0, 0);
}

// ---------------------------------------------------------------------------
// Prep: Wt[n*K+k] = bf16(W[k*N+n]). 32x32 tile, 256 thr (32x8).
// ---------------------------------------------------------------------------
__global__ __launch_bounds__(256)
void transpose_cvt(const float* __restrict__ W, short* __restrict__ Wt, int K, int N)
{
    __shared__ short tile[32][33];
    const int k0 = blockIdx.x * 32, n0 = blockIdx.y * 32;
    const int tx = threadIdx.x & 31, ty = threadIdx.x >> 5;
#pragma unroll
    for (int i = 0; i < 4; i++)
        tile[ty + i*8][tx] = f2bs(W[(size_t)(k0 + ty + i*8) * N + n0 + tx]);
    __syncthreads();
#pragma unroll
    for (int i = 0; i < 4; i++)
        Wt[(size_t)(n0 + ty + i*8) * K + k0 + tx] = tile[tx][ty + i*8];
}

// Prep: dst = bf16(src * (*scalep or 1))
__global__ __launch_bounds__(256)
void cvt_scale(const float* __restrict__ src, const float* __restrict__ scalep,
               short* __restrict__ dst, int n)
{
    const int i = blockIdx.x * 256 + threadIdx.x;
    const float s = scalep ? scalep[0] : 1.f;
    if (i < n) dst[i] = f2bs(src[i] * s);
}

// ---------------------------------------------------------------------------
// C[M,N](bf16) = act(A[M,K](bf16) @ Bt[N,K](bf16)^T + bias[N](f32))
// m97 recipe: 128x128 tile, BK=32, 4 waves (2x2 of 64x64), 16x16x32 MFMA,
// global_load_lds width=16 staging, ds_read_b128 fragment loads, fp32 acc.
// M,N,K must be multiples of 128/128/32 (all shapes here qualify).
// ---------------------------------------------------------------------------
__global__ __launch_bounds__(256)
void gemm_mfma(const short* __restrict__ A, const short* __restrict__ Bt,
               const float* __restrict__ bias, short* __restrict__ C,
               int M, int N, int K, int gelu)
{
    __shared__ short sA[128*32];
    __shared__ short sB[128*32];
    const int tid  = threadIdx.x;
    const int w    = tid >> 6;
    const int lane = tid & 63;
    const int l16  = lane & 15, g = lane >> 4;
    const int wm   = w & 1, wn = w >> 1;
    const size_t m0 = (size_t)blockIdx.y * 128, n0 = (size_t)blockIdx.x * 128;

    const int srow = lane >> 2;     // 0..15 row within 16-row segment
    const int kc   = lane & 3;      // 16B chunk within 32-elem k-row

    f32x4 acc[4][4];
#pragma unroll
    for (int i = 0; i < 4; i++)
#pragma unroll
        for (int j = 0; j < 4; j++) acc[i][j] = (f32x4){0.f,0.f,0.f,0.f};

    // staging: segment s = w*2+t covers rows s*16..s*16+15 (lane i -> row s*16+i/4, 16B chunk i%4)
    const short* gA0 = A  + (m0 + w*32 +      srow) * (size_t)K + kc*8;
    const short* gA1 = A  + (m0 + w*32 + 16 + srow) * (size_t)K + kc*8;
    const short* gB0 = Bt + (n0 + w*32 +      srow) * (size_t)K + kc*8;
    const short* gB1 = Bt + (n0 + w*32 + 16 + srow) * (size_t)K + kc*8;
    short* lA0 = &sA[(w*32     )*32];
    short* lA1 = &sA[(w*32 + 16)*32];
    short* lB0 = &sB[(w*32     )*32];
    short* lB1 = &sB[(w*32 + 16)*32];

    for (int k0 = 0; k0 < K; k0 += 32) {
        gl2lds16(gA0 + k0, lA0);
        gl2lds16(gA1 + k0, lA1);
        gl2lds16(gB0 + k0, lB0);
        gl2lds16(gB1 + k0, lB1);
        __syncthreads();            // drains vmcnt (compiler-inserted) + barrier

        bf16x8 af[4], bf[4];
#pragma unroll
        for (int mt = 0; mt < 4; mt++)
            af[mt] = *(const bf16x8*)&sA[(wm*64 + mt*16 + l16)*32 + g*8];
#pragma unroll
        for (int nt = 0; nt < 4; nt++)
            bf[nt] = *(const bf16x8*)&sB[(wn*64 + nt*16 + l16)*32 + g*8];
#pragma unroll
        for (int mt = 0; mt < 4; mt++)
#pragma unroll
            for (int nt = 0; nt < 4; nt++)
                acc[mt][nt] = __builtin_amdgcn_mfma_f32_16x16x32_bf16(
                                  af[mt], bf[nt], acc[mt][nt], 0, 0, 0);
        __syncthreads();
    }

#pragma unroll
    for (int mt = 0; mt < 4; mt++) {
#pragma unroll
        for (int r = 0; r < 4; r++) {
            const size_t row = m0 + wm*64 + mt*16 + g*4 + r;
#pragma unroll
            for (int nt = 0; nt < 4; nt++) {
                const size_t col = n0 + wn*64 + nt*16 + l16;
                float v = acc[mt][nt][r] + bias[col];
                if (gelu) v = 0.5f * v * (1.f + erff(v * 0.70710678118f));
                C[row * N + col] = f2bs(v);
            }
        }
    }
}

// ---------------------------------------------------------------------------
// Flash attention (bf16 MFMA) on packed QKV [M][2304] (Q|K|V each 768).
// Block = (64-query tile, head, batch), 4 waves x 16 queries.
// bC = bf16(bias_matrix * coef) precomputed. CTX out bf16 [M][768].
// ---------------------------------------------------------------------------
__global__ __launch_bounds__(256)
void attn_fused(const short* __restrict__ QKV, const float* __restrict__ mask,
                const short* __restrict__ bC, short* __restrict__ CTX)
{
    __shared__ short sK [64*72];
    __shared__ short sVt[64*72];
    __shared__ short sP [64*72];
    __shared__ float sMask[64];

    const int q0  = blockIdx.x * 64;
    const int h   = blockIdx.y;
    const int b   = blockIdx.z;
    const int tid = threadIdx.x;
    const int w   = tid >> 6;
    const int lane = tid & 63;
    const int l16 = lane & 15;
    const int g   = lane >> 4;
    const float scale = 0.125f;

    // Q A-frags straight from global bf16 (held all kernel)
    const short* qrow = QKV + ((size_t)(b*SS) + q0 + w*16 + l16) * 2304 + h*64;
    bf16x8 aQ0 = *(const bf16x8*)(qrow + g*8);
    bf16x8 aQ1 = *(const bf16x8*)(qrow + 32 + g*8);

    f32x4 O[4];
#pragma unroll
    for (int d = 0; d < 4; d++) O[d] = (f32x4){0.f,0.f,0.f,0.f};
    float m_i[4], l_i[4];
#pragma unroll
    for (int r = 0; r < 4; r++) { m_i[r] = -1e30f; l_i[r] = 0.f; }

    const int srow = tid >> 2;      // 0..63 key row
    const int scg  = tid & 3;       // 16-elem dim group

    for (int k0 = 0; k0 < SS; k0 += 64) {
        const size_t rbase = ((size_t)(b*SS) + k0 + srow) * 2304 + h*64 + scg*16;
        {   // K tile [key][dim]
            bf16x8 t0 = *(const bf16x8*)(QKV + rbase + 768);
            bf16x8 t1 = *(const bf16x8*)(QKV + rbase + 768 + 8);
            *(bf16x8*)&sK[srow*72 + scg*16]     = t0;
            *(bf16x8*)&sK[srow*72 + scg*16 + 8] = t1;
        }
        {   // V transposed [dim][key]
            bf16x8 t0 = *(const bf16x8*)(QKV + rbase + 1536);
            bf16x8 t1 = *(const bf16x8*)(QKV + rbase + 1536 + 8);
#pragma unroll
            for (int i = 0; i < 8; i++) sVt[(scg*16 + i  )*72 + srow] = t0[i];
#pragma unroll
            for (int i = 0; i < 8; i++) sVt[(scg*16 + 8+i)*72 + srow] = t1[i];
        }
        if (tid < 64) sMask[tid] = (1.f - mask[b*SS + k0 + tid]) * (-10000.0f);
        __syncthreads();

        float S[4][4];
#pragma unroll
        for (int t16 = 0; t16 < 4; t16++) {
            bf16x8 b0 = *(const bf16x8*)&sK[(t16*16 + l16)*72 + g*8];
            bf16x8 b1 = *(const bf16x8*)&sK[(t16*16 + l16)*72 + 32 + g*8];
            f32x4 c = (f32x4){0.f,0.f,0.f,0.f};
            c = __builtin_amdgcn_mfma_f32_16x16x32_bf16(aQ0, b0, c, 0, 0, 0);
            c = __builtin_amdgcn_mfma_f32_16x16x32_bf16(aQ1, b1, c, 0, 0, 0);
            const float madd = sMask[t16*16 + l16];
            const int   kcol = k0 + t16*16 + l16;
#pragma unroll
            for (int r = 0; r < 4; r++) {
                const int qg = q0 + w*16 + g*4 + r;
                S[t16][r] = c[r]*scale + bs2f(bC[(size_t)qg*SS + kcol]) + madd;
            }
        }

#pragma unroll
        for (int r = 0; r < 4; r++) {
            float mx = fmaxf(fmaxf(S[0][r], S[1][r]), fmaxf(S[2][r], S[3][r]));
            mx = fmaxf(mx, __shfl_xor(mx, 1));
            mx = fmaxf(mx, __shfl_xor(mx, 2));
            mx = fmaxf(mx, __shfl_xor(mx, 4));
            mx = fmaxf(mx, __shfl_xor(mx, 8));
            const float mnew  = fmaxf(m_i[r], mx);
            const float alpha = __expf(m_i[r] - mnew);
            float rs = 0.f;
#pragma unroll
            for (int t16 = 0; t16 < 4; t16++) {
                float p = __expf(S[t16][r] - mnew);
                S[t16][r] = p;
                rs += p;
            }
            rs += __shfl_xor(rs, 1);
            rs += __shfl_xor(rs, 2);
            rs += __shfl_xor(rs, 4);
            rs += __shfl_xor(rs, 8);
            l_i[r] = l_i[r]*alpha + rs;
            m_i[r] = mnew;
#pragma unroll
            for (int d = 0; d < 4; d++) O[d][r] *= alpha;
        }

#pragma unroll
        for (int t16 = 0; t16 < 4; t16++)
#pragma unroll
            for (int r = 0; r < 4; r++)
                sP[(w*16 + g*4 + r)*72 + t16*16 + l16] = f2bs(S[t16][r]);
        __syncthreads();

        bf16x8 aP0 = *(const bf16x8*)&sP[(w*16 + l16)*72 + g*8];
        bf16x8 aP1 = *(const bf16x8*)&sP[(w*16 + l16)*72 + 32 + g*8];
#pragma unroll
        for (int d = 0; d < 4; d++) {
            bf16x8 v0 = *(const bf16x8*)&sVt[(d*16 + l16)*72 + g*8];
            bf16x8 v1 = *(const bf16x8*)&sVt[(d*16 + l16)*72 + 32 + g*8];
            O[d] = __builtin_amdgcn_mfma_f32_16x16x32_bf16(aP0, v0, O[d], 0, 0, 0);
            O[d] = __builtin_amdgcn_mfma_f32_16x16x32_bf16(aP1, v1, O[d], 0, 0, 0);
        }
        __syncthreads();
    }

#pragma unroll
    for (int d = 0; d < 4; d++)
#pragma unroll
        for (int r = 0; r < 4; r++)
            CTX[((size_t)(b*SS) + q0 + w*16 + g*4 + r)*HH + h*64 + d*16 + l16]
                = f2bs(O[d][r] / l_i[r]);
}

// ---------------------------------------------------------------------------
// Out(bf16) = LayerNorm(A + R) * g + beta; optional fp32 copy to OutF.
// fp32 stats; safe for Out == A.
// ---------------------------------------------------------------------------
__global__ __launch_bounds__(256)
void add_ln(const short* __restrict__ A, const short* __restrict__ R,
            const float* __restrict__ g, const float* __restrict__ beta,
            short* __restrict__ Out, float* __restrict__ OutF)
{
    const int row = blockIdx.x;
    const int tid = threadIdx.x;
    __shared__ float vals[HH];
    __shared__ float rbuf[256];

    float s = 0.f;
    for (int c = tid; c < HH; c += 256) {
        float v = bs2f(A[(size_t)row*HH + c]) + bs2f(R[(size_t)row*HH + c]);
        vals[c] = v;
        s += v;
    }
    rbuf[tid] = s; __syncthreads();
    for (int off = 128; off > 0; off >>= 1) {
        if (tid < off) rbuf[tid] += rbuf[tid + off];
        __syncthreads();
    }
    const float mu = rbuf[0] * (1.f / HH); __syncthreads();

    float s2 = 0.f;
    for (int c = tid; c < HH; c += 256) {
        float d = vals[c] - mu;
        s2 += d * d;
    }
    rbuf[tid] = s2; __syncthreads();
    for (int off = 128; off > 0; off >>= 1) {
        if (tid < off) rbuf[tid] += rbuf[tid + off];
        __syncthreads();
    }
    const float rstd = rsqrtf(rbuf[0] * (1.f / HH) + 1e-12f); __syncthreads();

    for (int c = tid; c < HH; c += 256) {
        float v = (vals[c] - mu) * rstd * g[c] + beta[c];
        Out[(size_t)row*HH + c] = f2bs(v);
        if (OutF) OutF[(size_t)row*HH + c] = v;
    }
}

// ---------------------------------------------------------------------------
extern "C" void kernel_launch(void* const* d_in, const int* in_sizes, int n_in,
                              void* d_out, int out_size, void* d_ws, size_t ws_size,
                              hipStream_t stream)
{
    const float* hs    = (const float*)d_in[0];
    const float* mask  = (const float*)d_in[1];
    const float* biasM = (const float*)d_in[2];
    const float* coef  = (const float*)d_in[3];
    const float* Wq    = (const float*)d_in[4];
    const float* bq    = (const float*)d_in[5];
    const float* Wk    = (const float*)d_in[6];
    const float* bk    = (const float*)d_in[7];
    const float* Wv    = (const float*)d_in[8];
    const float* bv    = (const float*)d_in[9];
    const float* Wo    = (const float*)d_in[10];
    const float* bo    = (const float*)d_in[11];
    const float* ln1g  = (const float*)d_in[12];
    const float* ln1b  = (const float*)d_in[13];
    const float* Wi    = (const float*)d_in[14];
    const float* bi    = (const float*)d_in[15];
    const float* Wo2   = (const float*)d_in[16];
    const float* bo2   = (const float*)d_in[17];
    const float* ln2g  = (const float*)d_in[18];
    const float* ln2b  = (const float*)d_in[19];

    // ---- workspace layout (74.5 MB; <= 72 MiB proven budget) ----
    const size_t sH   = (size_t)MTOK * HH;        // 3,145,728
    const size_t sQKV = (size_t)MTOK * 3 * HH;    // 9,437,184
    const size_t WPL  = 7077888;                  // bf16 weight elems per layer
    short* wt   = (short*)d_ws;                   // [2*WPL]
    float* bqkv = (float*)(wt + 2*WPL);           // [2*2304]
    short* bC   = (short*)(bqkv + 2*2304);        // [SS*SS]
    short* X    = bC + (size_t)SS*SS;
    short* X2   = X  + sH;
    short* QKV  = X2 + sH;
    short* CTX  = QKV + sQKV;                     // end = CTX + sH
    short* TMP  = QKV;                            // alias (QKV dead)
    short* INTER= QKV;                            // alias: QKV+CTX = exactly MTOK*FFD
    short* TMP2 = X;                              // alias (X dead)

    const dim3 blk(256);

    // ---- prep: weights -> bf16 transposed; bias_matrix*coef -> bf16; hs -> bf16
    for (int l = 0; l < NLAYER; l++) {
        short* wl = wt + (size_t)l * WPL;
        short* qkvt = wl;                         // [2304][768]
        short* wot  = wl + 1769472;               // [768][768]
        short* wit  = wl + 2359296;               // [3072][768]
        short* wo2t = wl + 4718592;               // [768][3072]
        transpose_cvt<<<dim3(24,24), blk, 0, stream>>>(Wq + (size_t)l*HH*HH, qkvt,            HH, HH);
        transpose_cvt<<<dim3(24,24), blk, 0, stream>>>(Wk + (size_t)l*HH*HH, qkvt + 768*768,  HH, HH);
        transpose_cvt<<<dim3(24,24), blk, 0, stream>>>(Wv + (size_t)l*HH*HH, qkvt + 1536*768, HH, HH);
        transpose_cvt<<<dim3(24,24), blk, 0, stream>>>(Wo + (size_t)l*HH*HH, wot,             HH, HH);
        transpose_cvt<<<dim3(24,96), blk, 0, stream>>>(Wi + (size_t)l*HH*FFD, wit,            HH, FFD);
        transpose_cvt<<<dim3(96,24), blk, 0, stream>>>(Wo2+ (size_t)l*FFD*HH, wo2t,           FFD, HH);
        hipMemcpyAsync(bqkv + l*2304,        bq + l*HH, HH*4, hipMemcpyDeviceToDevice, stream);
        hipMemcpyAsync(bqkv + l*2304 + 768,  bk + l*HH, HH*4, hipMemcpyDeviceToDevice, stream);
        hipMemcpyAsync(bqkv + l*2304 + 1536, bv + l*HH, HH*4, hipMemcpyDeviceToDevice, stream);
    }
    cvt_scale<<<dim3((SS*SS + 255)/256), blk, 0, stream>>>(biasM, coef, bC, SS*SS);
    cvt_scale<<<dim3((int)((sH + 255)/256)), blk, 0, stream>>>(hs, nullptr, X, (int)sH);

    const dim3 gQKV(2304/128, MTOK/128);   // [18, 32]
    const dim3 gH  (HH/128,   MTOK/128);   // [ 6, 32]
    const dim3 gFF (FFD/128,  MTOK/128);   // [24, 32]
    const dim3 gA  (SS/64, NHEAD, BB);     // [32, 12, 2]

    for (int l = 0; l < NLAYER; l++) {
        short* wl = wt + (size_t)l * WPL;
        gemm_mfma<<<gQKV, blk, 0, stream>>>(X, wl, bqkv + l*2304, QKV, MTOK, 3*HH, HH, 0);
        attn_fused<<<gA, blk, 0, stream>>>(QKV, mask, bC, CTX);
        gemm_mfma<<<gH, blk, 0, stream>>>(CTX, wl + 1769472, bo + l*HH, TMP, MTOK, HH, HH, 0);
        add_ln<<<MTOK, blk, 0, stream>>>(TMP, X, ln1g + l*HH, ln1b + l*HH, X2, nullptr);
        gemm_mfma<<<gFF, blk, 0, stream>>>(X2, wl + 2359296, bi + l*FFD, INTER, MTOK, FFD, HH, 1);
        gemm_mfma<<<gH, blk, 0, stream>>>(INTER, wl + 4718592, bo2 + l*HH, TMP2, MTOK, HH, FFD, 0);
        add_ln<<<MTOK, blk, 0, stream>>>(TMP2, X2, ln2g + l*HH, ln2b + l*HH, X,
                                         (l == NLAYER-1) ? (float*)d_out : nullptr);
    }
}